// Round 9
// baseline (58.783 us; speedup 1.0000x reference)
//
#include <hip/hip_runtime.h>

#define NGUESS 256
#define CPG 20      // chunks per group
#define NGROUP 50   // 1000 chunks / CPG

// AES inverse S-box: INV_SBOX[SBOX[x]] == x
__device__ __constant__ int INV_SBOXD[256] = {
   82,   9, 106, 213,  48,  54, 165,  56, 191,  64, 163, 158, 129, 243, 215, 251,
  124, 227,  57, 130, 155,  47, 255, 135,  52, 142,  67,  68, 196, 222, 233, 203,
   84, 123, 148,  50, 166, 194,  35,  61, 238,  76, 149,  11,  66, 250, 195,  78,
    8,  46, 161, 102,  40, 217,  36, 178, 118,  91, 162,  73, 109, 139, 209,  37,
  114, 248, 246, 100, 134, 104, 152,  22, 212, 164,  92, 204,  93, 101, 182, 146,
  108, 112,  72,  80, 253, 237, 185, 218,  94,  21,  70,  87, 167, 141, 157, 132,
  144, 216, 171,   0, 140, 188, 211,  10, 247, 228,  88,   5, 184, 179,  69,   6,
  208,  44,  30, 143, 202,  63,  15,   2, 193, 175, 189,   3,   1,  19, 138, 107,
   58, 145,  17,  65,  79, 103, 220, 234, 151, 242, 207, 206, 240, 180, 230, 115,
  150, 172, 116,  34, 231, 173,  53, 133, 226, 249,  55, 232,  28, 117, 223, 110,
   71, 241,  26, 113,  29,  41, 197, 137, 111, 183,  98,  14, 170,  24, 190,  27,
  252,  86,  62,  75, 198, 210, 121,  32, 154, 219, 192, 254, 120, 205,  90, 244,
   31, 221, 168,  51, 136,   7, 199,  49, 177,  18,  16,  89,  39, 128, 236,  95,
   96,  81, 127, 169,  25, 181,  74,  13,  45, 229, 122, 159, 147, 201, 156, 239,
  160, 224,  59,  77, 174,  42, 245, 176, 200, 235, 187,  60, 131,  83, 153,  97,
   23,  43,   4, 126, 186, 119, 214,  38, 225, 105,  20,  99,  85,  33,  12, 125
};

// K1: identical to round 8 (best known). Launched TWICE this round as a
// measurement: the second launch rewrites identical cs values (idempotent,
// deterministic), so total_r9 - total_r8 = K1's true warm duration — which
// the top-5 rocprof view has never shown (masked by 57us harness fills).
__global__ __launch_bounds__(256) void k_chunksums(const float* __restrict__ pred,
                                                   const int* __restrict__ meta,
                                                   float* __restrict__ cs) {
  __shared__ float prow[4][4][NGUESS];  // [wave][slot][256] 16 KB
  __shared__ float red[4][NGUESS];      // 4 KB

  const int tid = threadIdx.x;
  const int w = tid >> 6;
  const int l = tid & 63;
  const size_t base = (size_t)blockIdx.x * 100 + (size_t)w * 25;

  const int c0 = l << 2;
  const int t0 = INV_SBOXD[c0 + 0];
  const int t1 = INV_SBOXD[c0 + 1];
  const int t2 = INV_SBOXD[c0 + 2];
  const int t3 = INV_SBOXD[c0 + 3];

  const float* rp = pred + (base << 8) + c0;

  auto scat = [&](float* s, const float4& v) {
    s[t0] = __logf(v.x);
    s[t1] = __logf(v.y);
    s[t2] = __logf(v.z);
    s[t3] = __logf(v.w);
  };

  float s0 = 0.f, s1 = 0.f, s2 = 0.f, s3 = 0.f;
  auto gath = [&](const float* ps, int m) {
    const int mx = m ^ l;
    s0 += ps[mx];
    s1 += ps[mx ^ 64];
    s2 += ps[mx ^ 128];
    s3 += ps[mx ^ 192];
  };

  // prime: pairs 0 (rows 0,1) and 1 (rows 2,3)
  float4 vA = *reinterpret_cast<const float4*>(rp + 0 * NGUESS);
  float4 vB = *reinterpret_cast<const float4*>(rp + 1 * NGUESS);
  float4 nA = *reinterpret_cast<const float4*>(rp + 2 * NGUESS);
  float4 nB = *reinterpret_cast<const float4*>(rp + 3 * NGUESS);
  int pmA = meta[base + 0];
  int pmB = meta[base + 1];

  // peel pair 0: scatter rows 0,1 -> slots 0,1 (no gather yet)
  scat(prow[w][0], vA);
  scat(prow[w][1], vB);

#pragma unroll
  for (int p = 1; p < 12; ++p) {
    vA = nA; vB = nB;
    const int rA = (2 * p + 2 <= 24) ? (2 * p + 2) : 24;   // clamped tail
    const int rB = (2 * p + 3 <= 24) ? (2 * p + 3) : 24;
    nA = *reinterpret_cast<const float4*>(rp + (size_t)rA * NGUESS);
    nB = *reinterpret_cast<const float4*>(rp + (size_t)rB * NGUESS);
    const int mA = meta[base + 2 * p];
    const int mB = meta[base + 2 * p + 1];

    // scatter pair p into slots 2*(p&1), 2*(p&1)+1
    float* sA = prow[w][2 * (p & 1)];
    scat(sA, vA);
    scat(sA + NGUESS, vB);

    // gather pair p-1 from slots 2*((p-1)&1), +1 (data landed; DS in-order)
    const float* gA = prow[w][2 * ((p & 1) ^ 1)];
    gath(gA, pmA);
    gath(gA + NGUESS, pmB);

    pmA = mA; pmB = mB;
  }

  // tail: row 24 (sits in nA after last rotation), scatter to slot 0
  scat(prow[w][0], nA);
  gath(prow[w][2], pmA);
  gath(prow[w][3], pmB);
  gath(prow[w][0], meta[base + 24]);

  red[w][l]       = s0;
  red[w][l + 64]  = s1;
  red[w][l + 128] = s2;
  red[w][l + 192] = s3;
  __syncthreads();
  cs[((size_t)blockIdx.x) * NGUESS + tid] =
      red[0][tid] + red[1][tid] + red[2][tid] + red[3][tid];
}

// K2a: per-group (20-chunk) sums in double. 200 blocks x 64 threads.
__global__ __launch_bounds__(64) void k_groupsum(const float* __restrict__ cs,
                                                 double* __restrict__ gsum) {
  const int b = blockIdx.x >> 2;
  const int g = ((blockIdx.x & 3) << 6) + threadIdx.x;
  double s0 = 0.0, s1 = 0.0;
#pragma unroll
  for (int c = 0; c < CPG; c += 2) {
    s0 += (double)cs[(size_t)(b * CPG + c) * NGUESS + g];
    s1 += (double)cs[(size_t)(b * CPG + c + 1) * NGUESS + g];
  }
  gsum[(size_t)b * NGUESS + g] = s0 + s1;
}

// K2b: one block per chunk; group prefix (masked fixed-trip, fully pipelined)
// + intra-group chunk rows; rank via ballot.
__global__ __launch_bounds__(256) void k_ranks(const float* __restrict__ cs,
                                               const double* __restrict__ gsum,
                                               const int* __restrict__ ckp,
                                               int* __restrict__ outRanks,
                                               int* __restrict__ outX) {
  const int c = blockIdx.x;       // chunk id
  const int g = threadIdx.x;
  const int grp = c / CPG;
  const int rem = c - grp * CPG;  // chunks included within group: 0..rem
  double acc = 0.0, acc2 = 0.0;
#pragma unroll
  for (int bb = 0; bb < NGROUP; bb += 2) {
    if (bb     < grp) acc  += gsum[(size_t)bb       * NGUESS + g];
    if (bb + 1 < grp) acc2 += gsum[(size_t)(bb + 1) * NGUESS + g];
  }
#pragma unroll
  for (int t = 0; t < CPG; t += 2) {
    if (t     <= rem) acc  += (double)cs[(size_t)(grp * CPG + t)     * NGUESS + g];
    if (t + 1 <= rem) acc2 += (double)cs[(size_t)(grp * CPG + t + 1) * NGUESS + g];
  }
  acc += acc2;

  __shared__ double keysh;
  __shared__ int cnt;
  const int ck = *ckp;
  if (g == ck) keysh = acc;
  if (g == 0) cnt = 0;
  __syncthreads();
  const unsigned long long mball = __ballot(acc > keysh);
  if ((g & 63) == 0) atomicAdd(&cnt, (int)__popcll(mball));
  __syncthreads();
  if (g == 0) {
    outRanks[c] = cnt;
    outX[c] = (c + 1) * 100;
  }
}

extern "C" void kernel_launch(void* const* d_in, const int* in_sizes, int n_in,
                              void* d_out, int out_size, void* d_ws, size_t ws_size,
                              hipStream_t stream) {
  const float* pred = (const float*)d_in[0];
  const int* meta   = (const int*)d_in[1];
  // d_in[2] = guess_range (256), d_in[3] = correct_key (34), d_in[4] = step (100)
  const int* ckp    = (const int*)d_in[3];

  const int N = in_sizes[1];             // 100000
  const int num_chunks = N / 100;        // 1000
  const int ngroups = num_chunks / CPG;  // 50

  float*  cs   = (float*)d_ws;                                            // [1000][256] f32
  double* gsum = (double*)((char*)d_ws +
                           (size_t)num_chunks * NGUESS * sizeof(float));  // [50][256] f64

  int* out = (int*)d_out;                // ranks[0..nc), x_rank[nc..2nc)

  // MEASUREMENT: K1 launched twice (idempotent). Delta vs round 8 = K1_warm.
  k_chunksums<<<num_chunks,  256, 0, stream>>>(pred, meta, cs);
  k_chunksums<<<num_chunks,  256, 0, stream>>>(pred, meta, cs);
  k_groupsum <<<ngroups * 4,  64, 0, stream>>>(cs, gsum);
  k_ranks    <<<num_chunks,  256, 0, stream>>>(cs, gsum, ckp, out, out + num_chunks);
}